// Round 21
// baseline (618.901 us; speedup 1.0000x reference)
//
#include <hip/hip_runtime.h>
#include <math.h>

#define TWO_PI 6.283185307179586f

// HARNESS MODEL (verified R8-R20): d_out = 33,362,176 f32 = Re(out), [bc][l][m].
// Math: xr[c][k][m] = (2pi/720) * sum_n x[c][k][n] * cos(2pi n m/720)
//       out[c][l][m] = sum_k xr[c][k][m] * W[m][l][k]
// R21: s1 diagnosis — LDS-READ-BW BOUND (14 b128/wave/iter x 14 waves vs
// 85 B/cy ceiling = the invariant ~2770 cy/iter across R14-R20 schedules).
// Fix: (1) 32x32x16 MFMA (2x FLOP per LDS byte), (2) A fragments built
// per-lane in REGISTERS (no LDS, no A barrier dep; accuracy proven R19),
// (3) B-only LDS (24 KB) via DMA with chunk swizzle c^=(row>>1)&3 on BOTH
// source and read (8-access/bank minimum). s2/transpose unchanged.

typedef __attribute__((ext_vector_type(8))) short bf16x8;
typedef __attribute__((ext_vector_type(4))) float f32x4;
typedef __attribute__((ext_vector_type(16))) float f32x16;

union BFU { uint4 u; bf16x8 v; };

__device__ inline unsigned short f2bf(float f) {
    union { float f; unsigned int u; } v; v.f = f;
    unsigned int u = v.u;
    return (unsigned short)((u + 0x7fffu + ((u >> 16) & 1u)) >> 16);  // RNE
}
__device__ inline float bf2f(unsigned short h) {
    union { unsigned int u; float f; } v; v.u = ((unsigned int)h) << 16;
    return v.f;
}
__device__ inline unsigned int packhl(float v) {
    unsigned short h = f2bf(v);
    unsigned short l = f2bf(v - bf2f(h));
    return (unsigned int)h | ((unsigned int)l << 16);
}
__device__ inline void split2(float a, float b, unsigned int& hh, unsigned int& ll) {
    unsigned short ha = f2bf(a), hb = f2bf(b);
    unsigned short la = f2bf(a - bf2f(ha)), lb = f2bf(b - bf2f(hb));
    hh = (unsigned int)ha | ((unsigned int)hb << 16);
    ll = (unsigned int)la | ((unsigned int)lb << 16);
}
// async global->LDS, 16B per lane; dest = wave-uniform base + lane*16
__device__ inline void gload_lds16(const void* g, void* l) {
    __builtin_amdgcn_global_load_lds(
        (const __attribute__((address_space(1))) unsigned int*)g,
        (__attribute__((address_space(3))) unsigned int*)l, 16, 0, 0);
}
// bijective chunked XCD swizzle (m204)
__device__ inline int xcd_work(int bid, int nwg) {
    int q = nwg >> 3, r = nwg & 7;
    int xcd = bid & 7, ord = bid >> 3;
    return (xcd < r ? xcd * (q + 1) : r * (q + 1) + (xcd - r) * q) + ord;
}

// ---------------- tables: EcT_hi/lo [384][384] bf16, EcT[m][n] = sigma*cos, n<=360 ----------------
__global__ void build_ect(unsigned short* __restrict__ Eh,
                          unsigned short* __restrict__ El) {
    const float sigma = TWO_PI / 720.0f;
    const int total = 384 * 384;
    for (int i = blockIdx.x * blockDim.x + threadIdx.x; i < total;
         i += gridDim.x * blockDim.x) {
        int m = i / 384, n = i % 384;
        float v = 0.f;
        if (m < 361 && n <= 360) {
            int r = (n * m) % 720;  // exact phase reduction
            v = sigma * cosf((float)r * (TWO_PI / 720.0f));
        }
        unsigned short h = f2bf(v);
        Eh[i] = h;
        El[i] = f2bf(v - bf2f(h));
    }
}

// ---------------- stage 1: xr[m][q] = sum_{n<=360} y[q][n]*EcT[m][n] ----------------
// y[n] = x[n]+x[720-n] (n=1..359), y0=x0, y360=x360.  12 iters of K=32,
// 32x32x16 MFMA, tile 128q x 96m, 4 waves (one 32-row q slice each, 3 m-subtiles).
// A: per-lane reg fold+split. B: LDS dbuf via DMA, chunk-swizzled.
__global__ __launch_bounds__(256, 3) void s1_mfma(
    const float* __restrict__ x, const unsigned short* __restrict__ Eh,
    const unsigned short* __restrict__ El, unsigned int* __restrict__ xrp,
    const int Q) {
    __shared__ short Bt[2][6144];   // [buf][(tab*96+row)*4 + cswz] x 8 shorts; 24 KB

    const int work = xcd_work(blockIdx.x, gridDim.x);
    const int q0 = (work >> 2) * 128;
    const int m0g = (work & 3) * 96;
    const int t = threadIdx.x;
    const int lane = t & 63, wv = t >> 6;
    const int lrow = lane & 31, lhk = lane >> 5;   // fragment row / k-half

    const int aq = q0 + wv * 32 + lrow;            // this lane's A (q) row
    const float* arow = x + (size_t)aq * 720;
    const bool qv = (aq < Q);

    // B DMA source pointers: 3 chunks/thread, chunk-index pre-swizzled so the
    // linear-dest DMA lands data where the swizzled reads expect it (rule #21).
    const unsigned short* bsrc[3];
#pragma unroll
    for (int i = 0; i < 3; ++i) {
        int id = t + i * 256;             // 0..767
        int tab = id / 384, rem = id % 384;
        int row = rem >> 2, c = rem & 3;
        int csw = c ^ ((row >> 1) & 3);
        bsrc[i] = (tab ? El : Eh) + (size_t)(m0g + row) * 384 + csw * 8;
    }

    // per-lane swizzled B-read chunk ids (row>>1 factor is nj-invariant: 32/2%4==0)
    const int fsw = (lrow >> 1) & 3;
    const int c0 = (0 + lhk) ^ fsw;       // kc=0 chunk
    const int c1 = (2 + lhk) ^ fsw;       // kc=1 chunk

    f32x16 acc[3];
#pragma unroll
    for (int nj = 0; nj < 3; ++nj)
#pragma unroll
        for (int r = 0; r < 16; ++r) acc[nj][r] = 0.f;

    float4 fw0[2], fw1[2], rv0[2], rv1[2];   // raw A prefetch (2 runs of 8)
    bf16x8 ah[2], al[2];                     // current A fragments

    // load raw x for run R starting at col KG (8 forward + reversed pair)
#define S1_LOADRUN(R, KG)                                                  \
    {                                                                      \
        int kg = (KG);                                                     \
        fw0[R] = make_float4(0.f, 0.f, 0.f, 0.f);                          \
        fw1[R] = fw0[R]; rv0[R] = fw0[R]; rv1[R] = fw0[R];                 \
        if (qv) {                                                          \
            if (kg <= 352) {                                               \
                fw0[R] = *(const float4*)(arow + kg);                      \
                fw1[R] = *(const float4*)(arow + kg + 4);                  \
            } else if (kg == 360) {                                        \
                fw0[R].x = arow[360];                                      \
            }                                                              \
            if (kg >= 8 && kg <= 352) {                                    \
                rv0[R] = *(const float4*)(arow + 713 - kg);                \
                rv1[R] = *(const float4*)(arow + 717 - kg);                \
            } else if (kg == 0) {                                          \
                float tm[8];                                               \
                _Pragma("unroll") for (int i = 0; i < 8; ++i)              \
                    tm[i] = (7 - i >= 1) ? arow[713 + i] : 0.f;            \
                rv0[R] = make_float4(tm[0], tm[1], tm[2], tm[3]);          \
                rv1[R] = make_float4(tm[4], tm[5], tm[6], tm[7]);          \
            }                                                              \
        }                                                                  \
    }
#define S1_LOADRAW(IT)                                                    \
    {                                                                     \
        S1_LOADRUN(0, (IT) * 32 + lhk * 8);                               \
        S1_LOADRUN(1, (IT) * 32 + 16 + lhk * 8);                          \
    }
    // fold + RNE split run R -> ah[R]/al[R]
#define S1_MAKE(R)                                                        \
    {                                                                     \
        float y0 = fw0[R].x + rv1[R].w, y1 = fw0[R].y + rv1[R].z;         \
        float y2 = fw0[R].z + rv1[R].y, y3 = fw0[R].w + rv1[R].x;         \
        float y4 = fw1[R].x + rv0[R].w, y5 = fw1[R].y + rv0[R].z;         \
        float y6 = fw1[R].z + rv0[R].y, y7 = fw1[R].w + rv0[R].x;         \
        BFU hu, lu;                                                       \
        split2(y0, y1, hu.u.x, lu.u.x);                                   \
        split2(y2, y3, hu.u.y, lu.u.y);                                   \
        split2(y4, y5, hu.u.z, lu.u.z);                                   \
        split2(y6, y7, hu.u.w, lu.u.w);                                   \
        ah[R] = hu.v; al[R] = lu.v;                                       \
    }
#define S1_COPYB(NB, IT)                                                  \
    {                                                                     \
        char* bb = (char*)&Bt[NB][0];                                     \
        _Pragma("unroll") for (int i = 0; i < 3; ++i)                     \
            gload_lds16(bsrc[i] + (IT) * 32, bb + (t + i * 256) * 16);    \
    }

    // prologue
    S1_COPYB(0, 0);
    S1_LOADRAW(0);
    S1_MAKE(0);
    S1_MAKE(1);
    __syncthreads();   // drains DMA vmcnt
    int cur = 0;
    for (int it = 0; it < 12; ++it) {
        const int nb = cur ^ 1;
        if (it + 1 < 12) {
            S1_COPYB(nb, it + 1);    // DMA runs under the MFMA phase
            S1_LOADRAW(it + 1);      // A raw loads in flight under MFMAs
        }
        const char* bufc = (const char*)&Bt[cur][0];
#pragma unroll
        for (int nj = 0; nj < 3; ++nj) {
            const int rb = nj * 2048 + lrow * 64;
            bf16x8 bh0 = *(const bf16x8*)(bufc + rb + c0 * 16);
            bf16x8 bl0 = *(const bf16x8*)(bufc + 6144 + rb + c0 * 16);
            bf16x8 bh1 = *(const bf16x8*)(bufc + rb + c1 * 16);
            bf16x8 bl1 = *(const bf16x8*)(bufc + 6144 + rb + c1 * 16);
            acc[nj] = __builtin_amdgcn_mfma_f32_32x32x16_bf16(ah[0], bh0, acc[nj], 0, 0, 0);
            acc[nj] = __builtin_amdgcn_mfma_f32_32x32x16_bf16(ah[0], bl0, acc[nj], 0, 0, 0);
            acc[nj] = __builtin_amdgcn_mfma_f32_32x32x16_bf16(al[0], bh0, acc[nj], 0, 0, 0);
            acc[nj] = __builtin_amdgcn_mfma_f32_32x32x16_bf16(ah[1], bh1, acc[nj], 0, 0, 0);
            acc[nj] = __builtin_amdgcn_mfma_f32_32x32x16_bf16(ah[1], bl1, acc[nj], 0, 0, 0);
            acc[nj] = __builtin_amdgcn_mfma_f32_32x32x16_bf16(al[1], bh1, acc[nj], 0, 0, 0);
        }
        if (it + 1 < 12) {
            S1_MAKE(0);              // fold/split next A after MFMAs
            S1_MAKE(1);
            __syncthreads();         // next B buffer ready; readers done with cur
            cur = nb;
        }
    }

    // epilogue: 32x32 D map (guide m74/m101): col=lane&31, row=(r&3)+8*(r>>2)+4*(lane>>5)
#pragma unroll
    for (int nj = 0; nj < 3; ++nj) {
        int m = m0g + nj * 32 + lrow;
        if (m >= 361) continue;
        size_t base = (size_t)m * Q;
#pragma unroll
        for (int r = 0; r < 16; ++r) {
            int q = q0 + wv * 32 + (r & 3) + 8 * (r >> 2) + 4 * lhk;
            if (q < Q) xrp[base + q] = packhl(acc[nj][r]);
        }
    }
}

// ---------------- stage 2: per-m GEMM, tile 128bc x 64l (R14 proven form) ----------------
__global__ __launch_bounds__(256, 4) void s2_mfma(
    const unsigned int* __restrict__ xrp, const float* __restrict__ W,
    float* __restrict__ stg, const int CH) {
    __shared__ short Ah[128][40], Al[128][40];   // 10 KB each
    __shared__ short Bh[64][40], Bl[64][40];     // 5 KB each -> 30 KB

    const int work = xcd_work(blockIdx.x, gridDim.x);
    const int m = work / 12;
    const int rem = work % 12;
    const int half = rem / 6, lt = rem % 6;
    const int l0 = lt * 64;
    if (l0 + 63 < m) return;          // dead tile: zero-filled by transpose
    const int bcbase = half * 128;
    if (bcbase >= CH) return;
    const int Q = CH * 361;
    const int t = threadIdx.x;
    const int lane = t & 63, wv = t >> 6;
    const int lr = lane & 15, lk = lane >> 4;
    const int wbc = wv >> 1, wl = wv & 1;

    const unsigned int* Am = xrp + (size_t)m * Q;
    const float* Wm = W + (size_t)m * 130321;

    f32x4 acc[4][2];
#pragma unroll
    for (int fi = 0; fi < 4; ++fi)
#pragma unroll
        for (int ni = 0; ni < 2; ++ni)
#pragma unroll
            for (int r = 0; r < 4; ++r) acc[fi][ni][r] = 0.f;

    unsigned int pa0[8], pa1[8];
    float wva[4], wvb[4];

#define S2_LOADR(K0)                                                          \
    {                                                                         \
        _Pragma("unroll") for (int i = 0; i < 8; ++i) {                       \
            int id = t + i * 256;                                             \
            int r = id >> 4, kp = id & 15;                                    \
            int bc = bcbase + r, kg = (K0) + kp * 2;                          \
            unsigned int p0 = 0, p1 = 0;                                      \
            if (bc < CH) {                                                    \
                size_t base = (size_t)bc * 361;                               \
                if (kg < 361) p0 = Am[base + kg];                             \
                if (kg + 1 < 361) p1 = Am[base + kg + 1];                     \
            }                                                                 \
            pa0[i] = p0; pa1[i] = p1;                                         \
        }                                                                     \
        _Pragma("unroll") for (int i = 0; i < 4; ++i) {                       \
            int id = t + i * 256;                                             \
            int r = id >> 4, kp = id & 15;                                    \
            int l = l0 + r, kg = (K0) + kp * 2;                               \
            float va = 0.f, vb = 0.f;                                         \
            if (l < 361) {                                                    \
                size_t base = (size_t)l * 361;                                \
                if (kg < 361) va = Wm[base + kg];                             \
                if (kg + 1 < 361) vb = Wm[base + kg + 1];                     \
            }                                                                 \
            wva[i] = va; wvb[i] = vb;                                         \
        }                                                                     \
    }
#define S2_WRITES()                                                           \
    {                                                                         \
        _Pragma("unroll") for (int i = 0; i < 8; ++i) {                       \
            int id = t + i * 256;                                             \
            int r = id >> 4, kp = id & 15;                                    \
            *(unsigned int*)&Ah[r][kp * 2] =                                  \
                (pa0[i] & 0xffffu) | (pa1[i] << 16);                          \
            *(unsigned int*)&Al[r][kp * 2] =                                  \
                (pa0[i] >> 16) | (pa1[i] & 0xffff0000u);                      \
        }                                                                     \
        _Pragma("unroll") for (int i = 0; i < 4; ++i) {                       \
            int id = t + i * 256;                                             \
            int r = id >> 4, kp = id & 15;                                    \
            unsigned int hh, ll;                                              \
            split2(wva[i], wvb[i], hh, ll);                                   \
            *(unsigned int*)&Bh[r][kp * 2] = hh;                              \
            *(unsigned int*)&Bl[r][kp * 2] = ll;                              \
        }                                                                     \
    }

    S2_LOADR(0);
    S2_WRITES();
    __syncthreads();
    for (int it = 0; it < 12; ++it) {
        if (it + 1 < 12) S2_LOADR((it + 1) * 32);
#pragma unroll
        for (int fi = 0; fi < 4; ++fi) {
            bf16x8 ah = *(const bf16x8*)&Ah[wbc * 64 + fi * 16 + lr][lk * 8];
            bf16x8 al = *(const bf16x8*)&Al[wbc * 64 + fi * 16 + lr][lk * 8];
#pragma unroll
            for (int ni = 0; ni < 2; ++ni) {
                bf16x8 bh = *(const bf16x8*)&Bh[wl * 32 + ni * 16 + lr][lk * 8];
                bf16x8 bl = *(const bf16x8*)&Bl[wl * 32 + ni * 16 + lr][lk * 8];
                acc[fi][ni] = __builtin_amdgcn_mfma_f32_16x16x32_bf16(ah, bh, acc[fi][ni], 0, 0, 0);
                acc[fi][ni] = __builtin_amdgcn_mfma_f32_16x16x32_bf16(ah, bl, acc[fi][ni], 0, 0, 0);
                acc[fi][ni] = __builtin_amdgcn_mfma_f32_16x16x32_bf16(al, bh, acc[fi][ni], 0, 0, 0);
            }
        }
        __syncthreads();
        if (it + 1 < 12) {
            S2_WRITES();
            __syncthreads();
        }
    }

    // epilogue: stg[(m*CH+bc)*361+l]
#pragma unroll
    for (int fi = 0; fi < 4; ++fi) {
#pragma unroll
        for (int ni = 0; ni < 2; ++ni) {
            int l = l0 + wl * 32 + ni * 16 + lr;
#pragma unroll
            for (int reg = 0; reg < 4; ++reg) {
                int bc = bcbase + wbc * 64 + fi * 16 + lk * 4 + reg;
                if (bc < CH && l < 361)
                    stg[((size_t)m * CH + bc) * 361 + l] = acc[fi][ni][reg];
            }
        }
    }
}

// ---------------- transpose stg [m][q'] -> out, zero-filling dead tiles ----------------
__global__ __launch_bounds__(256) void transpose_out(const float* __restrict__ stg,
                                                     float* __restrict__ out,
                                                     const int c0, const int CH) {
    __shared__ float tile[32][33];
    const int Q = CH * 361;
    const int m0 = blockIdx.y * 32, q0 = blockIdx.x * 32;
    const int tx = threadIdx.x & 31, ty = threadIdx.x >> 5;
    for (int i = ty; i < 32; i += 8) {
        int mm = m0 + i, q = q0 + tx;
        float v = 0.f;
        if (mm < 361 && q < Q) {
            int l = q % 361;
            if ((l | 63) >= mm) v = stg[(size_t)mm * Q + q];  // live 64-tile
        }
        tile[i][tx] = v;
    }
    __syncthreads();
    for (int i = ty; i < 32; i += 8) {
        int q = q0 + i, mm = m0 + tx;
        if (mm < 361 && q < Q)
            out[((size_t)c0 * 361 + q) * 361 + mm] = tile[tx][i];
    }
}

extern "C" void kernel_launch(void* const* d_in, const int* in_sizes, int n_in,
                              void* d_out, int out_size, void* d_ws, size_t ws_size,
                              hipStream_t stream) {
    (void)out_size;
    // select inputs by element count: x = 66,539,520; W = 47,045,881
    const float* x = (const float*)d_in[0];
    const float* W = (const float*)d_in[1];
    if (n_in >= 2 && (in_sizes[0] == 47045881 || in_sizes[1] == 66539520)) {
        x = (const float*)d_in[1];
        W = (const float*)d_in[0];
    }
    float* out = (float*)d_out;

    // ws layout (bytes): EcT_hi [384][384] | EcT_lo | xrp (uint) | stg (f32)
    const size_t offEh = 0;
    const size_t offEl = 294912;                 // 384*384*2
    const size_t offData = 589824;

    const int cands[6] = {256, 128, 64, 32, 16, 8};
    int CH = 0;
    for (int i = 0; i < 6; ++i) {
        size_t need = offData + 2ull * cands[i] * 130321ull * 4ull;
        if (need <= ws_size) { CH = cands[i]; break; }
    }
    if (!CH) return;  // workspace too small: fail visibly, don't fault

    unsigned short* Eh = (unsigned short*)((char*)d_ws + offEh);
    unsigned short* El = (unsigned short*)((char*)d_ws + offEl);
    unsigned int* xrp = (unsigned int*)((char*)d_ws + offData);
    float* stg = (float*)((char*)d_ws + offData + (size_t)CH * 130321ull * 4ull);

    build_ect<<<256, 256, 0, stream>>>(Eh, El);

    const int Q = CH * 361;
    const int qt = (Q + 127) / 128;
    for (int c0 = 0; c0 < 256; c0 += CH) {
        s1_mfma<<<qt * 4, 256, 0, stream>>>(
            x + (size_t)c0 * 361 * 720, Eh, El, xrp, Q);
        s2_mfma<<<361 * 12, 256, 0, stream>>>(xrp, W, stg, CH);
        transpose_out<<<dim3((Q + 31) / 32, 12), 256, 0, stream>>>(stg, out, c0, CH);
    }
}